// Round 12
// baseline (564.947 us; speedup 1.0000x reference)
//
#include <hip/hip_runtime.h>

#define CI   128
#define TT   8192
#define CO   256
#define KW   9
#define NQ   5
#define PADL 4
#define KDIM (CI*KW)       // 1152
#define NSTEP 36           // K32 steps per q
#define NF (NQ*NSTEP)      // 180
#define BCO  128
#define BT   128
#define XROWS 136
#define XPITCH 136         // 272B rows: 17 x 16B granules (odd) -> octet-clean b128 reads

typedef __attribute__((ext_vector_type(8))) short short8;
typedef __attribute__((ext_vector_type(4))) float float4v;

static __device__ __forceinline__ short f2bf(float f) {
  union { float f; unsigned u; } c; c.f = f;
  unsigned u = c.u;
  return (short)((u + 0x7FFFu + ((u >> 16) & 1u)) >> 16);  // RNE
}

static __device__ __forceinline__ float tanh_fast(float z) {
  float e = __expf(2.f * z);
  return (e - 1.f) / (e + 1.f);
}

// ---- kernel 1: pack conv_weights (CO,CI,KW,NQ) fp32 into per-lane fragment
// stream: coalesced 1KB lines per (fi, wm, m), L2-resident (2.95MB < 4MB/XCD).
__global__ void selfonn_wpack(const float* __restrict__ w, short* __restrict__ wpk, int n) {
  int o = blockIdx.x * 256 + threadIdx.x;
  if (o >= n) return;
  int j    = o & 7;
  int lane = (o >> 3) & 63;
  int m    = (o >> 9) & 3;
  int wm   = (o >> 11) & 1;
  int ft   = o >> 12;          // 0..2*NF-1
  int ch   = ft / NF;
  int fi   = ft - ch * NF;
  int q    = fi / NSTEP;
  int step = fi - q * NSTEP;
  int k    = step >> 2;
  int cib  = step & 3;
  int l15  = lane & 15;
  int lg   = lane >> 4;
  int co   = ch * 128 + wm * 64 + m * 16 + l15;
  int ci   = cib * 32 + lg * 8 + j;
  wpk[o] = f2bf(w[((co * CI + ci) * KW + k) * NQ + q]);
}

// ---- kernel 2: fused implicit-GEMM conv + nonlinearities + weighted sum ----
// Barrier-free main loop; weights stream global->VGPR (ring-3, depth-2);
// x tile static in LDS; inner 36-step K-loop FULLY UNROLLED with literal
// step indices (B offsets fold into ds_read immediates); 2 blocks/CU.
__global__ __launch_bounds__(256, 2) void selfonn_main(
    const float* __restrict__ x, const short* __restrict__ wpk,
    const float* __restrict__ probs, float* __restrict__ out) {

  __shared__ __align__(16) short xs[XROWS][XPITCH];   // 36992 B
  __shared__ float opw[BCO][NQ];                      // 2560 B

  const int tid  = threadIdx.x;
  const int lane = tid & 63;
  const int wid  = tid >> 6;   // 0..3
  const int wm   = wid >> 1;   // co half
  const int wt   = wid & 1;    // t half
  const int l15  = lane & 15;
  const int lg   = lane >> 4;  // 0..3
  const int b    = blockIdx.z;
  const int ch   = blockIdx.y;          // co 128-half of 256
  const int co0  = ch * BCO;
  const int t0   = blockIdx.x * BT;

  // operator softmax -> LDS
  if (tid < BCO) {
    float p[NQ];
    float mx = -1e30f;
    #pragma unroll
    for (int j = 0; j < NQ; ++j) { p[j] = probs[(co0 + tid) * NQ + j]; mx = fmaxf(mx, p[j]); }
    float s = 0.f;
    #pragma unroll
    for (int j = 0; j < NQ; ++j) { p[j] = __expf(p[j] - mx); s += p[j]; }
    float inv = 1.0f / s;
    #pragma unroll
    for (int j = 0; j < NQ; ++j) opw[tid][j] = p[j] * inv;
  }

  // stage x tile once (t-transposed, bf16): xs[tl][ci] = x[b][ci][t0-4+tl]
  const float* xb = x + (size_t)b * CI * TT;
  #pragma unroll
  for (int it = 0; it < 17; ++it) {
    int cell = tid + it * 256;          // 0..4351
    int ci = cell & (CI - 1);
    int tc = cell >> 7;                 // 0..33
    int tg = t0 - PADL + tc * 4;
    float4v v = {0.f, 0.f, 0.f, 0.f};
    if (tg >= 0 && tg <= TT - 4)
      v = *(const float4v*)(xb + (size_t)ci * TT + tg);
    int tl = tc * 4;
    xs[tl + 0][ci] = f2bf(v[0]);
    xs[tl + 1][ci] = f2bf(v[1]);
    xs[tl + 2][ci] = f2bf(v[2]);
    xs[tl + 3][ci] = f2bf(v[3]);
  }

  // B-frag base pointers (LDS): 4 regs; all step offsets are literals on top
  const short* xbase0 = &xs[0][0] + (wt * 64 +  0 + l15) * XPITCH + (lg << 3);
  const short* xbase1 = &xs[0][0] + (wt * 64 + 16 + l15) * XPITCH + (lg << 3);
  const short* xbase2 = &xs[0][0] + (wt * 64 + 32 + l15) * XPITCH + (lg << 3);
  const short* xbase3 = &xs[0][0] + (wt * 64 + 48 + l15) * XPITCH + (lg << 3);

  // wave's packed-weight stream pointer (shorts): fi=0 frag base
  const short* const wp0 = wpk + ((size_t)(ch * NF) * 2 + wm) * 2048 + lane * 8;
  const short* wp = wp0;

  float4v oacc[4][4];
  float4v acc[4][4];
  #pragma unroll
  for (int m = 0; m < 4; ++m)
    #pragma unroll
    for (int n = 0; n < 4; ++n) {
      oacc[m][n] = (float4v){0.f, 0.f, 0.f, 0.f};
      acc[m][n]  = (float4v){0.f, 0.f, 0.f, 0.f};
    }

  __syncthreads();   // xs/opw ready; no further barriers

  short8 W0[4], W1[4], W2[4], BA[4], BB[4];
  // prologue: W(0)->W0, W(1)->W1, B(step0)->BA
  #pragma unroll
  for (int m = 0; m < 4; ++m) W0[m] = *(const short8*)(wp + m * 512);
  #pragma unroll
  for (int m = 0; m < 4; ++m) W1[m] = *(const short8*)(wp + 4096 + m * 512);
  wp += 8192;    // -> fi=2 frag base
  BA[0] = *(const short8*)(xbase0);
  BA[1] = *(const short8*)(xbase1);
  BA[2] = *(const short8*)(xbase2);
  BA[3] = *(const short8*)(xbase3);

  for (int q = 0; q < NQ; ++q) {
    const bool lastq = (q == NQ - 1);

    // STEP with LITERAL step index S: B offsets are compile-time immediates.
    #define STEP(S, CW, CB, NW, NB)                                      \
      {                                                                  \
        /* prefetch weight frags(fi+2); guard OOB on last q */           \
        const short* wq = ((S) >= 34 && lastq) ? wp0 : wp;               \
        _Pragma("unroll") for (int i = 0; i < 4; ++i)                    \
          NW[i] = *(const short8*)(wq + i * 512);                        \
        wp += 4096;                                                      \
        /* prefetch B frags(step S+1) — literal LDS offsets */           \
        {                                                                \
          constexpr int SN  = ((S) + 1) % NSTEP;                         \
          constexpr int OFF = (SN >> 2) * XPITCH + ((SN & 3) << 5);      \
          NB[0] = *(const short8*)(xbase0 + OFF);                        \
          NB[1] = *(const short8*)(xbase1 + OFF);                        \
          NB[2] = *(const short8*)(xbase2 + OFF);                        \
          NB[3] = *(const short8*)(xbase3 + OFF);                        \
        }                                                                \
        __builtin_amdgcn_s_setprio(1);                                   \
        _Pragma("unroll") for (int m = 0; m < 4; ++m)                    \
          _Pragma("unroll") for (int n = 0; n < 4; ++n)                  \
            acc[m][n] = __builtin_amdgcn_mfma_f32_16x16x32_bf16(         \
                CW[m], CB[n], acc[m][n], 0, 0, 0);                       \
        __builtin_amdgcn_s_setprio(0);                                   \
        if ((S) == NSTEP - 1) {                                          \
          /* fused epilogue for this q; also resets acc */               \
          _Pragma("unroll") for (int m = 0; m < 4; ++m) {                \
            _Pragma("unroll") for (int jj = 0; jj < 4; ++jj) {           \
              int co_l = wm * 64 + m * 16 + lg * 4 + jj;                 \
              float wqv = opw[co_l][q];                                  \
              _Pragma("unroll") for (int n = 0; n < 4; ++n) {            \
                float z = acc[m][n][jj];                                 \
                float f;                                                 \
                if (q == 0)      f = z;                                  \
                else if (q == 1) f = __sinf(z);                          \
                else if (q == 2) f = __cosf(z);                          \
                else if (q == 3) f = tanh_fast(z);                       \
                else             f = __expf(fminf(fmaxf(z, -8.f), 8.f)); \
                oacc[m][n][jj] += wqv * f;                               \
                acc[m][n][jj] = 0.f;                                     \
              }                                                          \
            }                                                            \
          }                                                              \
        }                                                                \
      }

    // 36 literal steps; W ring-3, B dbuf, pattern period 6
    STEP( 0, W0, BA, W2, BB)  STEP( 1, W1, BB, W0, BA)
    STEP( 2, W2, BA, W1, BB)  STEP( 3, W0, BB, W2, BA)
    STEP( 4, W1, BA, W0, BB)  STEP( 5, W2, BB, W1, BA)
    STEP( 6, W0, BA, W2, BB)  STEP( 7, W1, BB, W0, BA)
    STEP( 8, W2, BA, W1, BB)  STEP( 9, W0, BB, W2, BA)
    STEP(10, W1, BA, W0, BB)  STEP(11, W2, BB, W1, BA)
    STEP(12, W0, BA, W2, BB)  STEP(13, W1, BB, W0, BA)
    STEP(14, W2, BA, W1, BB)  STEP(15, W0, BB, W2, BA)
    STEP(16, W1, BA, W0, BB)  STEP(17, W2, BB, W1, BA)
    STEP(18, W0, BA, W2, BB)  STEP(19, W1, BB, W0, BA)
    STEP(20, W2, BA, W1, BB)  STEP(21, W0, BB, W2, BA)
    STEP(22, W1, BA, W0, BB)  STEP(23, W2, BB, W1, BA)
    STEP(24, W0, BA, W2, BB)  STEP(25, W1, BB, W0, BA)
    STEP(26, W2, BA, W1, BB)  STEP(27, W0, BB, W2, BA)
    STEP(28, W1, BA, W0, BB)  STEP(29, W2, BB, W1, BA)
    STEP(30, W0, BA, W2, BB)  STEP(31, W1, BB, W0, BA)
    STEP(32, W2, BA, W1, BB)  STEP(33, W0, BB, W2, BA)
    STEP(34, W1, BA, W0, BB)  STEP(35, W2, BB, W1, BA)
    #undef STEP
  }

  // store (B, CO, T) fp32
  float* ob = out + (size_t)(b * CO + co0) * TT;
  #pragma unroll
  for (int m = 0; m < 4; ++m) {
    #pragma unroll
    for (int jj = 0; jj < 4; ++jj) {
      int co_l = wm * 64 + m * 16 + lg * 4 + jj;
      int tcol = t0 + wt * 64 + l15;
      float* orow = ob + (size_t)co_l * TT + tcol;
      #pragma unroll
      for (int n = 0; n < 4; ++n)
        orow[n * 16] = oacc[m][n][jj];
    }
  }
}

extern "C" void kernel_launch(void* const* d_in, const int* in_sizes, int n_in,
                              void* d_out, int out_size, void* d_ws, size_t ws_size,
                              hipStream_t stream) {
  const float* x     = (const float*)d_in[0];
  const float* w     = (const float*)d_in[1];
  const float* probs = (const float*)d_in[2];
  float* out = (float*)d_out;
  short* wpk = (short*)d_ws;   // NQ*CO*KDIM*2 = 2.95 MB

  int nw = NQ * CO * KDIM;     // 1,474,560
  selfonn_wpack<<<dim3((nw + 255) / 256), 256, 0, stream>>>(w, wpk, nw);

  dim3 grid(TT / BT, CO / BCO, 16);
  selfonn_main<<<grid, 256, 0, stream>>>(x, wpk, probs, out);
}

// Round 14
// 340.569 us; speedup vs baseline: 1.6588x; 1.6588x over previous
//
#include <hip/hip_runtime.h>

#define CI   128
#define TT   8192
#define CO   256
#define KW   9
#define NQ   5
#define PADL 4
#define KDIM (CI*KW)       // 1152
#define NSTEP 36           // K32 steps per q
#define NF (NQ*NSTEP)      // 180
#define BCO  128
#define BT   128
#define XROWS 136
#define XPITCH 136         // 272B rows: 17 x 16B granules (odd) -> octet-clean b128 reads

typedef __attribute__((ext_vector_type(8))) short short8;
typedef __attribute__((ext_vector_type(4))) float float4v;

static __device__ __forceinline__ short f2bf(float f) {
  union { float f; unsigned u; } c; c.f = f;
  unsigned u = c.u;
  return (short)((u + 0x7FFFu + ((u >> 16) & 1u)) >> 16);  // RNE
}

static __device__ __forceinline__ float tanh_fast(float z) {
  float e = __expf(2.f * z);
  return (e - 1.f) / (e + 1.f);
}

// ---- kernel 1: pack conv_weights (CO,CI,KW,NQ) fp32 into per-lane fragment
// stream: coalesced 1KB lines per (fi, wm, m), L2-resident (2.95MB < 4MB/XCD).
__global__ void selfonn_wpack(const float* __restrict__ w, short* __restrict__ wpk, int n) {
  int o = blockIdx.x * 256 + threadIdx.x;
  if (o >= n) return;
  int j    = o & 7;
  int lane = (o >> 3) & 63;
  int m    = (o >> 9) & 3;
  int wm   = (o >> 11) & 1;
  int ft   = o >> 12;          // 0..2*NF-1
  int ch   = ft / NF;
  int fi   = ft - ch * NF;
  int q    = fi / NSTEP;
  int step = fi - q * NSTEP;
  int k    = step >> 2;
  int cib  = step & 3;
  int l15  = lane & 15;
  int lg   = lane >> 4;
  int co   = ch * 128 + wm * 64 + m * 16 + l15;
  int ci   = cib * 32 + lg * 8 + j;
  wpk[o] = f2bf(w[((co * CI + ci) * KW + k) * NQ + q]);
}

// ---- kernel 2: fused implicit-GEMM conv + nonlinearities + weighted sum ----
// Barrier-free main loop; weights stream global->VGPR (ring-3, depth-2);
// x tile static in LDS; 12-step unrolled inner body with LITERAL ds offsets
// (B addressing VALU ~0); q and g loops pinned no-unroll; 2 blocks/CU.
__global__ __launch_bounds__(256, 2) void selfonn_main(
    const float* __restrict__ x, const short* __restrict__ wpk,
    const float* __restrict__ probs, float* __restrict__ out) {

  __shared__ __align__(16) short xs[XROWS][XPITCH];   // 36992 B
  __shared__ float opw[BCO][NQ];                      // 2560 B

  const int tid  = threadIdx.x;
  const int lane = tid & 63;
  const int wid  = tid >> 6;   // 0..3
  const int wm   = wid >> 1;   // co half
  const int wt   = wid & 1;    // t half
  const int l15  = lane & 15;
  const int lg   = lane >> 4;  // 0..3
  const int b    = blockIdx.z;
  const int ch   = blockIdx.y;          // co 128-half of 256
  const int co0  = ch * BCO;
  const int t0   = blockIdx.x * BT;

  // operator softmax -> LDS
  if (tid < BCO) {
    float p[NQ];
    float mx = -1e30f;
    #pragma unroll
    for (int j = 0; j < NQ; ++j) { p[j] = probs[(co0 + tid) * NQ + j]; mx = fmaxf(mx, p[j]); }
    float s = 0.f;
    #pragma unroll
    for (int j = 0; j < NQ; ++j) { p[j] = __expf(p[j] - mx); s += p[j]; }
    float inv = 1.0f / s;
    #pragma unroll
    for (int j = 0; j < NQ; ++j) opw[tid][j] = p[j] * inv;
  }

  // stage x tile once (t-transposed, bf16): xs[tl][ci] = x[b][ci][t0-4+tl]
  const float* xb = x + (size_t)b * CI * TT;
  #pragma unroll
  for (int it = 0; it < 17; ++it) {
    int cell = tid + it * 256;          // 0..4351
    int ci = cell & (CI - 1);
    int tc = cell >> 7;                 // 0..33
    int tg = t0 - PADL + tc * 4;
    float4v v = {0.f, 0.f, 0.f, 0.f};
    if (tg >= 0 && tg <= TT - 4)
      v = *(const float4v*)(xb + (size_t)ci * TT + tg);
    int tl = tc * 4;
    xs[tl + 0][ci] = f2bf(v[0]);
    xs[tl + 1][ci] = f2bf(v[1]);
    xs[tl + 2][ci] = f2bf(v[2]);
    xs[tl + 3][ci] = f2bf(v[3]);
  }

  // B-frag base pointers (LDS, shorts)
  const short* const xbase0 = &xs[0][0] + (wt * 64 +  0 + l15) * XPITCH + (lg << 3);
  const short* const xbase1 = &xs[0][0] + (wt * 64 + 16 + l15) * XPITCH + (lg << 3);
  const short* const xbase2 = &xs[0][0] + (wt * 64 + 32 + l15) * XPITCH + (lg << 3);
  const short* const xbase3 = &xs[0][0] + (wt * 64 + 48 + l15) * XPITCH + (lg << 3);

  // wave's packed-weight stream pointer (shorts): fi=0 frag base
  const short* const wp0 = wpk + ((size_t)(ch * NF) * 2 + wm) * 2048 + lane * 8;
  const short* wp = wp0;

  float4v oacc[4][4];
  float4v acc[4][4];
  #pragma unroll
  for (int m = 0; m < 4; ++m)
    #pragma unroll
    for (int n = 0; n < 4; ++n) {
      oacc[m][n] = (float4v){0.f, 0.f, 0.f, 0.f};
      acc[m][n]  = (float4v){0.f, 0.f, 0.f, 0.f};
    }

  __syncthreads();   // xs/opw ready; no further barriers

  short8 W0[4], W1[4], W2[4], BA[4], BB[4];
  // prologue: W(0)->W0, W(1)->W1, B(step0)->BA
  #pragma unroll
  for (int m = 0; m < 4; ++m) W0[m] = *(const short8*)(wp + m * 512);
  #pragma unroll
  for (int m = 0; m < 4; ++m) W1[m] = *(const short8*)(wp + 4096 + m * 512);
  wp += 8192;    // -> fi=2 frag base (fi stride = 4096 shorts)
  BA[0] = *(const short8*)(xbase0);
  BA[1] = *(const short8*)(xbase1);
  BA[2] = *(const short8*)(xbase2);
  BA[3] = *(const short8*)(xbase3);

  #pragma unroll 1
  for (int q = 0; q < NQ; ++q) {
    #pragma unroll 1
    for (int g = 0; g < 3; ++g) {
      // per-g bases: sq = g*12 + s; OFF(sq) = g*3*XPITCH + OFFs(s)
      const int goff  = g * (3 * XPITCH);
      const int gnoff = (g == 2) ? 0 : goff + 3 * XPITCH;   // for s==11 wrap
      const short* const xg0 = xbase0 + goff;
      const short* const xg1 = xbase1 + goff;
      const short* const xg2 = xbase2 + goff;
      const short* const xg3 = xbase3 + goff;
      const short* const xn0 = xbase0 + gnoff;
      const short* const xn1 = xbase1 + gnoff;
      const short* const xn2 = xbase2 + gnoff;
      const short* const xn3 = xbase3 + gnoff;
      const bool lastS = (q == NQ - 1) && (g == 2);

      // STEP with LITERAL s (0..11): B offsets fold into ds_read immediates.
      #define STEP(S, CW, CB, NW, NB)                                    \
        {                                                                \
          /* W prefetch (fi+2); clamp at kernel tail (reads wp0) */      \
          const short* wq = (((S) >= 10) && lastS) ? wp0 : wp;           \
          _Pragma("unroll") for (int i = 0; i < 4; ++i)                  \
            NW[i] = *(const short8*)(wq + i * 512);                      \
          wp += 4096;   /* one fi */                                     \
          /* B prefetch (sq+1), literal offsets */                       \
          if ((S) < 11) {                                                \
            constexpr int OFF = (((S)+1) >> 2) * XPITCH + ((((S)+1) & 3) << 5); \
            NB[0] = *(const short8*)(xg0 + OFF);                         \
            NB[1] = *(const short8*)(xg1 + OFF);                         \
            NB[2] = *(const short8*)(xg2 + OFF);                         \
            NB[3] = *(const short8*)(xg3 + OFF);                         \
          } else {                                                       \
            NB[0] = *(const short8*)(xn0);                               \
            NB[1] = *(const short8*)(xn1);                               \
            NB[2] = *(const short8*)(xn2);                               \
            NB[3] = *(const short8*)(xn3);                               \
          }                                                              \
          __builtin_amdgcn_s_setprio(1);                                 \
          _Pragma("unroll") for (int m = 0; m < 4; ++m)                  \
            _Pragma("unroll") for (int n = 0; n < 4; ++n)                \
              acc[m][n] = __builtin_amdgcn_mfma_f32_16x16x32_bf16(       \
                  CW[m], CB[n], acc[m][n], 0, 0, 0);                     \
          __builtin_amdgcn_s_setprio(0);                                 \
        }

      STEP( 0, W0, BA, W2, BB)  STEP( 1, W1, BB, W0, BA)
      STEP( 2, W2, BA, W1, BB)  STEP( 3, W0, BB, W2, BA)
      STEP( 4, W1, BA, W0, BB)  STEP( 5, W2, BB, W1, BA)
      STEP( 6, W0, BA, W2, BB)  STEP( 7, W1, BB, W0, BA)
      STEP( 8, W2, BA, W1, BB)  STEP( 9, W0, BB, W2, BA)
      STEP(10, W1, BA, W0, BB)  STEP(11, W2, BB, W1, BA)
      #undef STEP
    }

    // fused epilogue for this q (runtime q branch, 5x per kernel); resets acc
    #pragma unroll
    for (int m = 0; m < 4; ++m) {
      #pragma unroll
      for (int jj = 0; jj < 4; ++jj) {
        int co_l = wm * 64 + m * 16 + lg * 4 + jj;
        float wqv = opw[co_l][q];
        #pragma unroll
        for (int n = 0; n < 4; ++n) {
          float z = acc[m][n][jj];
          float f;
          if (q == 0)      f = z;
          else if (q == 1) f = __sinf(z);
          else if (q == 2) f = __cosf(z);
          else if (q == 3) f = tanh_fast(z);
          else             f = __expf(fminf(fmaxf(z, -8.f), 8.f));
          oacc[m][n][jj] += wqv * f;
          acc[m][n][jj] = 0.f;
        }
      }
    }
  }

  // store (B, CO, T) fp32
  float* ob = out + (size_t)(b * CO + co0) * TT;
  #pragma unroll
  for (int m = 0; m < 4; ++m) {
    #pragma unroll
    for (int jj = 0; jj < 4; ++jj) {
      int co_l = wm * 64 + m * 16 + lg * 4 + jj;
      int tcol = t0 + wt * 64 + l15;
      float* orow = ob + (size_t)co_l * TT + tcol;
      #pragma unroll
      for (int n = 0; n < 4; ++n)
        orow[n * 16] = oacc[m][n][jj];
    }
  }
}

extern "C" void kernel_launch(void* const* d_in, const int* in_sizes, int n_in,
                              void* d_out, int out_size, void* d_ws, size_t ws_size,
                              hipStream_t stream) {
  const float* x     = (const float*)d_in[0];
  const float* w     = (const float*)d_in[1];
  const float* probs = (const float*)d_in[2];
  float* out = (float*)d_out;
  short* wpk = (short*)d_ws;   // NQ*CO*KDIM*2 = 2.95 MB

  int nw = NQ * CO * KDIM;     // 1,474,560
  selfonn_wpack<<<dim3((nw + 255) / 256), 256, 0, stream>>>(w, wpk, nw);

  dim3 grid(TT / BT, CO / BCO, 16);
  selfonn_main<<<grid, 256, 0, stream>>>(x, wpk, probs, out);
}

// Round 15
// 339.910 us; speedup vs baseline: 1.6621x; 1.0019x over previous
//
#include <hip/hip_runtime.h>

#define CI   128
#define TT   8192
#define CO   256
#define KW   9
#define NQ   5
#define PADL 4
#define KDIM (CI*KW)       // 1152
#define NSTEP 36           // K32 steps per q
#define NF (NQ*NSTEP)      // 180
#define BCO  128
#define BT   128
#define XROWS 136
#define XPITCH 136         // 272B rows: 17 x 16B granules (odd) -> octet-clean b128 reads

typedef __attribute__((ext_vector_type(8))) short short8;
typedef __attribute__((ext_vector_type(4))) float float4v;

static __device__ __forceinline__ short f2bf(float f) {
  union { float f; unsigned u; } c; c.f = f;
  unsigned u = c.u;
  return (short)((u + 0x7FFFu + ((u >> 16) & 1u)) >> 16);  // RNE
}

// ---- kernel 1: pack conv_weights (CO,CI,KW,NQ) fp32 into per-lane fragment
// stream: coalesced 1KB lines per (fi, wm, m), L2-resident (2.95MB < 4MB/XCD).
__global__ void selfonn_wpack(const float* __restrict__ w, short* __restrict__ wpk, int n) {
  int o = blockIdx.x * 256 + threadIdx.x;
  if (o >= n) return;
  int j    = o & 7;
  int lane = (o >> 3) & 63;
  int m    = (o >> 9) & 3;
  int wm   = (o >> 11) & 1;
  int ft   = o >> 12;          // 0..2*NF-1
  int ch   = ft / NF;
  int fi   = ft - ch * NF;
  int q    = fi / NSTEP;
  int step = fi - q * NSTEP;
  int k    = step >> 2;
  int cib  = step & 3;
  int l15  = lane & 15;
  int lg   = lane >> 4;
  int co   = ch * 128 + wm * 64 + m * 16 + l15;
  int ci   = cib * 32 + lg * 8 + j;
  wpk[o] = f2bf(w[((co * CI + ci) * KW + k) * NQ + q]);
}

// ---- kernel 2: fused implicit-GEMM conv + nonlinearities + weighted sum ----
// Barrier-free; W stream global->VGPR (ring-3, depth-2, SGPR base);
// x tile static in LDS (coalesced staging); 12-step literal-offset body.
__global__ __launch_bounds__(256, 2) void selfonn_main(
    const float* __restrict__ x, const short* __restrict__ wpk,
    const float* __restrict__ probs, float* __restrict__ out) {

  __shared__ __align__(16) short xs[XROWS][XPITCH];   // 36992 B
  __shared__ float opw[BCO][NQ];                      // 2560 B

  const int tid  = threadIdx.x;
  const int lane = tid & 63;
  const int wid  = tid >> 6;   // 0..3
  const int wm   = __builtin_amdgcn_readfirstlane((tid >> 6) >> 1);  // co half (wave-uniform)
  const int wt   = wid & 1;    // t half
  const int l15  = lane & 15;
  const int lg   = lane >> 4;  // 0..3
  const int b    = blockIdx.z;
  const int ch   = blockIdx.y;          // co 128-half of 256
  const int co0  = ch * BCO;
  const int t0   = blockIdx.x * BT;

  // operator softmax -> LDS
  if (tid < BCO) {
    float p[NQ];
    float mx = -1e30f;
    #pragma unroll
    for (int j = 0; j < NQ; ++j) { p[j] = probs[(co0 + tid) * NQ + j]; mx = fmaxf(mx, p[j]); }
    float s = 0.f;
    #pragma unroll
    for (int j = 0; j < NQ; ++j) { p[j] = __expf(p[j] - mx); s += p[j]; }
    float inv = 1.0f / s;
    #pragma unroll
    for (int j = 0; j < NQ; ++j) opw[tid][j] = p[j] * inv;
  }

  // stage x tile once (t-transposed, bf16), COALESCED:
  // phase A: rows ci = wid*32 + 2i + (lane>>5), lanes 0-31/32-63 read 512B
  // contiguous (t4 = lane&31); phase B: tl 128..135 cleanup.
  const float* xb = x + (size_t)b * CI * TT;
  {
    const int t4a = lane & 31;
    const int rsel = lane >> 5;
    #pragma unroll
    for (int i = 0; i < 16; ++i) {
      int ci = wid * 32 + 2 * i + rsel;
      int tg = t0 - PADL + t4a * 4;
      float4v v = {0.f, 0.f, 0.f, 0.f};
      if (tg >= 0 && tg <= TT - 4)
        v = *(const float4v*)(xb + (size_t)ci * TT + tg);
      int tl = t4a * 4;
      xs[tl + 0][ci] = f2bf(v[0]);
      xs[tl + 1][ci] = f2bf(v[1]);
      xs[tl + 2][ci] = f2bf(v[2]);
      xs[tl + 3][ci] = f2bf(v[3]);
    }
    // phase B: t4 = 32,33
    int ci = tid >> 1;
    int t4 = 32 + (tid & 1);
    int tg = t0 - PADL + t4 * 4;
    float4v v = {0.f, 0.f, 0.f, 0.f};
    if (tg >= 0 && tg <= TT - 4)
      v = *(const float4v*)(xb + (size_t)ci * TT + tg);
    int tl = t4 * 4;
    xs[tl + 0][ci] = f2bf(v[0]);
    xs[tl + 1][ci] = f2bf(v[1]);
    xs[tl + 2][ci] = f2bf(v[2]);
    xs[tl + 3][ci] = f2bf(v[3]);
  }

  // single B base (shorts); all frag/step offsets are compile-time literals
  const short* const xbase = &xs[0][0] + (wt * 64 + l15) * XPITCH + (lg << 3);

  // W stream: SGPR-uniform row base + fixed per-lane voffset
  const short* const wrow0 = wpk + ((size_t)(ch * NF) * 2 + wm) * 2048;
  const short* wrow = wrow0;
  const int wvo = lane * 8;    // shorts

  float4v oacc[4][4];
  float4v acc[4][4];
  #pragma unroll
  for (int m = 0; m < 4; ++m)
    #pragma unroll
    for (int n = 0; n < 4; ++n) {
      oacc[m][n] = (float4v){0.f, 0.f, 0.f, 0.f};
      acc[m][n]  = (float4v){0.f, 0.f, 0.f, 0.f};
    }

  __syncthreads();   // xs/opw ready; no further barriers

  short8 W0[4], W1[4], W2[4], BA[4], BB[4];
  // prologue: W(0)->W0, W(1)->W1, B(step0)->BA
  #pragma unroll
  for (int i = 0; i < 4; ++i) W0[i] = *(const short8*)(wrow + wvo + i * 512);
  #pragma unroll
  for (int i = 0; i < 4; ++i) W1[i] = *(const short8*)(wrow + 4096 + wvo + i * 512);
  wrow += 8192;    // -> fi=2 base (fi stride = 4096 shorts)
  #pragma unroll
  for (int n = 0; n < 4; ++n)
    BA[n] = *(const short8*)(xbase + n * 16 * XPITCH);

  #pragma unroll 1
  for (int q = 0; q < NQ; ++q) {
    #pragma unroll 1
    for (int g = 0; g < 3; ++g) {
      const short* const xg = xbase + g * (3 * XPITCH);
      const short* const xn = xbase + ((g == 2) ? 0 : (g + 1) * (3 * XPITCH));
      const bool lastS = (q == NQ - 1) && (g == 2);

      // STEP, s literal 0..11: [B prefetch] [16 MFMA] [W prefetch after]
      #define STEP(S, CW, CB, NW, NB)                                    \
        {                                                                \
          if ((S) < 11) {                                                \
            constexpr int KN  = (((S) + 1) >> 2);                        \
            constexpr int CB4 = (((S) + 1) & 3) << 5;                    \
            NB[0] = *(const short8*)(xg + (0 * 16 + KN) * XPITCH + CB4); \
            NB[1] = *(const short8*)(xg + (1 * 16 + KN) * XPITCH + CB4); \
            NB[2] = *(const short8*)(xg + (2 * 16 + KN) * XPITCH + CB4); \
            NB[3] = *(const short8*)(xg + (3 * 16 + KN) * XPITCH + CB4); \
          } else {                                                       \
            NB[0] = *(const short8*)(xn + 0 * 16 * XPITCH);              \
            NB[1] = *(const short8*)(xn + 1 * 16 * XPITCH);              \
            NB[2] = *(const short8*)(xn + 2 * 16 * XPITCH);              \
            NB[3] = *(const short8*)(xn + 3 * 16 * XPITCH);              \
          }                                                              \
          __builtin_amdgcn_s_setprio(1);                                 \
          _Pragma("unroll") for (int m = 0; m < 4; ++m)                  \
            _Pragma("unroll") for (int n = 0; n < 4; ++n)                \
              acc[m][n] = __builtin_amdgcn_mfma_f32_16x16x32_bf16(       \
                  CW[m], CB[n], acc[m][n], 0, 0, 0);                     \
          __builtin_amdgcn_s_setprio(0);                                 \
          {                                                              \
            const short* wq = (((S) >= 10) && lastS) ? wrow0 : wrow;     \
            NW[0] = *(const short8*)(wq + wvo + 0 * 512);                \
            NW[1] = *(const short8*)(wq + wvo + 1 * 512);                \
            NW[2] = *(const short8*)(wq + wvo + 2 * 512);                \
            NW[3] = *(const short8*)(wq + wvo + 3 * 512);                \
            wrow += 4096;                                                \
          }                                                              \
        }

      STEP( 0, W0, BA, W2, BB)  STEP( 1, W1, BB, W0, BA)
      STEP( 2, W2, BA, W1, BB)  STEP( 3, W0, BB, W2, BA)
      STEP( 4, W1, BA, W0, BB)  STEP( 5, W2, BB, W1, BA)
      STEP( 6, W0, BA, W2, BB)  STEP( 7, W1, BB, W0, BA)
      STEP( 8, W2, BA, W1, BB)  STEP( 9, W0, BB, W2, BA)
      STEP(10, W1, BA, W0, BB)  STEP(11, W2, BB, W1, BA)
      #undef STEP
    }

    // fused epilogue for this q (5x per kernel); resets acc
    #pragma unroll
    for (int m = 0; m < 4; ++m) {
      #pragma unroll
      for (int jj = 0; jj < 4; ++jj) {
        int co_l = wm * 64 + m * 16 + lg * 4 + jj;
        float wqv = opw[co_l][q];
        #pragma unroll
        for (int n = 0; n < 4; ++n) {
          float z = acc[m][n][jj];
          float f;
          if (q == 0)      f = z;
          else if (q == 1) f = __sinf(z);
          else if (q == 2) f = __cosf(z);
          else if (q == 3) { float e = __expf(2.f * z); f = 1.f - 2.f / (e + 1.f); }
          else             f = __expf(fminf(fmaxf(z, -8.f), 8.f));
          oacc[m][n][jj] += wqv * f;
          acc[m][n][jj] = 0.f;
        }
      }
    }
  }

  // store (B, CO, T) fp32
  float* ob = out + (size_t)(b * CO + co0) * TT;
  #pragma unroll
  for (int m = 0; m < 4; ++m) {
    #pragma unroll
    for (int jj = 0; jj < 4; ++jj) {
      int co_l = wm * 64 + m * 16 + lg * 4 + jj;
      int tcol = t0 + wt * 64 + l15;
      float* orow = ob + (size_t)co_l * TT + tcol;
      #pragma unroll
      for (int n = 0; n < 4; ++n)
        orow[n * 16] = oacc[m][n][jj];
    }
  }
}

extern "C" void kernel_launch(void* const* d_in, const int* in_sizes, int n_in,
                              void* d_out, int out_size, void* d_ws, size_t ws_size,
                              hipStream_t stream) {
  const float* x     = (const float*)d_in[0];
  const float* w     = (const float*)d_in[1];
  const float* probs = (const float*)d_in[2];
  float* out = (float*)d_out;
  short* wpk = (short*)d_ws;   // NQ*CO*KDIM*2 = 2.95 MB

  int nw = NQ * CO * KDIM;     // 1,474,560
  selfonn_wpack<<<dim3((nw + 255) / 256), 256, 0, stream>>>(w, wpk, nw);

  dim3 grid(TT / BT, CO / BCO, 16);
  selfonn_main<<<grid, 256, 0, stream>>>(x, wpk, probs, out);
}